// Round 8
// baseline (39408.371 us; speedup 1.0000x reference)
//
#include <hip/hip_runtime.h>
#include <cstdint>
#include <cstddef>

// RecurrentEncoder: 2-layer LSTM, B=32, S=1024, E=H=512, f32.
// Round 8: R1/R5/R7 bit-identical absmax 0.06298828125 even after a terminal
// t=0 rewrite of outs -> k_rec's stores never landed -> the ONLY kernels with
// no observable effect are the hipLaunchCooperativeKernel dispatches -> that
// API fails in this harness (return unchecked). Fix: plain <<<>>> launches.
// The grid barrier is already a custom agent-scope atomic; co-residency is
// guaranteed by capacity (36.9KB LDS -> >=4 blocks/CU by LDS, >=1 by VGPR ->
// 256 blocks always resident on 256 CUs), so the spin barrier cannot deadlock.
// Cell math: f64 exp/tanh + explicit __fmul_rn/__fadd_rn (kept).
// Terminal k_fix3 t=0 rewrites kept as cheap insurance + diagnostic tripwire.

#define BB 32
#define SS 1024
#define EE 512
#define HH 512
#define GG 2048   // 4*H
#define NBLK 256
#define NTHR 256

// ---------------------------------------------------------------- embed
__global__ void k_embed3(const int* __restrict__ ids, const float* __restrict__ emb,
                         float* __restrict__ X, float* __restrict__ maskf) {
  int m    = blockIdx.x * 4 + (threadIdx.x >> 6);   // row (t*32+b)
  int lane = threadIdx.x & 63;
  int t = m >> 5, b = m & 31;
  int id = ids[b * SS + t];
  bool pad = (id == 0);
  if (lane == 0) maskf[t * BB + b] = pad ? 1.0f : 0.0f;
  const float4* src = reinterpret_cast<const float4*>(emb + (size_t)id * EE);
  float4*       dst = reinterpret_cast<float4*>(X + (size_t)m * EE);
  float4 z = make_float4(0.f, 0.f, 0.f, 0.f);
#pragma unroll
  for (int i = 0; i < 2; ++i) {
    int idx = lane + 64 * i;
    dst[idx] = pad ? z : src[idx];
  }
}

// ---------------------------------------------------------------- input GEMM
// C[m][n] = sum_k A[m][k]*W[n][k] + bih[n] + bhh[n];  M = rows of chunk, N=2048, K=512.
#define KT 16
__global__ __launch_bounds__(256) void k_gemm3(const float* __restrict__ A,
                                               const float* __restrict__ W,
                                               const float* __restrict__ bih,
                                               const float* __restrict__ bhh,
                                               float* __restrict__ C) {
  __shared__ float As[KT][132];   // [k][m], stride 132 (16B aligned, 2-way max)
  __shared__ float Ws[KT][132];   // [k][n]
  const int tid = threadIdx.x;
  const int bm = blockIdx.x, bn = blockIdx.y;
  const int lrow = tid >> 1, lk = (tid & 1) * 8;
  const float* Ag = A + (size_t)(bm * 128 + lrow) * 512 + lk;
  const float* Wg = W + (size_t)(bn * 128 + lrow) * 512 + lk;
  const int tx = tid & 15, ty = tid >> 4;
  float acc[8][8];
#pragma unroll
  for (int i = 0; i < 8; ++i)
#pragma unroll
    for (int j = 0; j < 8; ++j) acc[i][j] = 0.f;

  for (int k0 = 0; k0 < 512; k0 += KT) {
    float4 a0 = *reinterpret_cast<const float4*>(Ag + k0);
    float4 a1 = *reinterpret_cast<const float4*>(Ag + k0 + 4);
    float4 w0 = *reinterpret_cast<const float4*>(Wg + k0);
    float4 w1 = *reinterpret_cast<const float4*>(Wg + k0 + 4);
    __syncthreads();
    As[lk + 0][lrow] = a0.x; As[lk + 1][lrow] = a0.y; As[lk + 2][lrow] = a0.z; As[lk + 3][lrow] = a0.w;
    As[lk + 4][lrow] = a1.x; As[lk + 5][lrow] = a1.y; As[lk + 6][lrow] = a1.z; As[lk + 7][lrow] = a1.w;
    Ws[lk + 0][lrow] = w0.x; Ws[lk + 1][lrow] = w0.y; Ws[lk + 2][lrow] = w0.z; Ws[lk + 3][lrow] = w0.w;
    Ws[lk + 4][lrow] = w1.x; Ws[lk + 5][lrow] = w1.y; Ws[lk + 6][lrow] = w1.z; Ws[lk + 7][lrow] = w1.w;
    __syncthreads();
#pragma unroll
    for (int kk = 0; kk < KT; ++kk) {
      float4 av0 = *reinterpret_cast<const float4*>(&As[kk][ty * 4]);
      float4 av1 = *reinterpret_cast<const float4*>(&As[kk][64 + ty * 4]);
      float4 wv0 = *reinterpret_cast<const float4*>(&Ws[kk][tx * 4]);
      float4 wv1 = *reinterpret_cast<const float4*>(&Ws[kk][64 + tx * 4]);
      float am[8] = {av0.x, av0.y, av0.z, av0.w, av1.x, av1.y, av1.z, av1.w};
      float wm[8] = {wv0.x, wv0.y, wv0.z, wv0.w, wv1.x, wv1.y, wv1.z, wv1.w};
#pragma unroll
      for (int i = 0; i < 8; ++i)
#pragma unroll
        for (int j = 0; j < 8; ++j) acc[i][j] = fmaf(am[i], wm[j], acc[i][j]);
    }
  }
  // epilogue
  float bias[8];
#pragma unroll
  for (int j = 0; j < 8; ++j) {
    int c = bn * 128 + ((j < 4) ? tx * 4 + j : 64 + tx * 4 + (j - 4));
    bias[j] = bih[c] + bhh[c];
  }
#pragma unroll
  for (int i = 0; i < 8; ++i) {
    int r = bm * 128 + ((i < 4) ? ty * 4 + i : 64 + ty * 4 + (i - 4));
    float4 v0 = make_float4(acc[i][0] + bias[0], acc[i][1] + bias[1],
                            acc[i][2] + bias[2], acc[i][3] + bias[3]);
    float4 v1 = make_float4(acc[i][4] + bias[4], acc[i][5] + bias[5],
                            acc[i][6] + bias[6], acc[i][7] + bias[7]);
    *reinterpret_cast<float4*>(C + (size_t)r * GG + bn * 128 + tx * 4) = v0;
    *reinterpret_cast<float4*>(C + (size_t)r * GG + bn * 128 + 64 + tx * 4) = v1;
  }
}

// ---------------------------------------------------------------- cell math
// High-accuracy nonlinearities: f64 internally, one f32 rounding on output.
__device__ __forceinline__ float sig_hi(float x) {
  return (float)(1.0 / (1.0 + exp(-(double)x)));
}
__device__ __forceinline__ float tanh_hi(float x) {
  return (float)tanh((double)x);
}

// ---------------------------------------------------------------- recurrence
// Plain launch; custom agent-scope atomic grid barrier (all 256 blocks resident
// by capacity: LDS 36.9KB -> 4 blocks/CU possible, grid == #CUs).
__global__ __launch_bounds__(256, 1) void k_rec3(const float* __restrict__ whh,  // [2048][512] layer
                                                 const float* __restrict__ G,    // [len*32][2048]
                                                 float* __restrict__ Hout,       // [S][32][512]
                                                 float* __restrict__ hT,         // [2][512][32]
                                                 float* __restrict__ cst,        // [32][512] layer
                                                 unsigned int* __restrict__ cnt,
                                                 int s0, int len) {
  __shared__ float sh[9216];   // half-K h stage [256][36]; aliased: red [16][8][36] + gates @4608
  const int tid = threadIdx.x;
  const int bid = blockIdx.x;
  const int c0 = bid * 2;            // 2 h-columns per block
  const int r4 = tid >> 7;           // row group (rows 4*r4 .. +3)
  const int kq = (tid >> 3) & 15;    // k window (16 k per half)
  const int b4 = tid & 7;            // batch quad

  // weight-stationary: wreg[half][i][u] = w_hh[R(4*r4+i)][h*256 + kq*16 + u*4 .. +3]
  float4 wreg[2][4][4];
#pragma unroll
  for (int h = 0; h < 2; ++h)
#pragma unroll
    for (int i = 0; i < 4; ++i) {
      int r = 4 * r4 + i;
      int row = (r >> 1) * 512 + c0 + (r & 1);
#pragma unroll
      for (int u = 0; u < 4; ++u)
        wreg[h][i][u] = *reinterpret_cast<const float4*>(
            whh + (size_t)row * 512 + h * 256 + kq * 16 + u * 4);
    }

  const int rr = tid >> 5;           // reduce-role row 0..7
  const int rb = tid & 31;           // reduce-role batch
  const int Rred = (rr >> 1) * 512 + c0 + (rr & 1);
  const int cd = tid >> 5, cb = tid & 31;   // cell role (tid<64): d, b
  const int ccol = c0 + cd;
  float creg = 0.f;
  if (s0 > 0 && tid < 64) creg = cst[cb * 512 + ccol];

  for (int ts = 0; ts < len; ++ts) {
    const int t = s0 + ts;
    const int pr = (t - 1) & 1, pw = t & 1;
    float gpre = G[((size_t)ts * 32 + rb) * GG + Rred];   // prefetch gate-input
    float4 acc4[4];
#pragma unroll
    for (int i = 0; i < 4; ++i) acc4[i] = make_float4(0.f, 0.f, 0.f, 0.f);

#pragma unroll
    for (int h = 0; h < 2; ++h) {
      // ---- stage half of h_{t-1}: global [k][b] -> LDS [k][b] stride 36
      if (t > 0) {
        const float* src = hT + pr * 16384 + h * 8192;
#pragma unroll
        for (int it = 0; it < 8; ++it) {
          int f4 = tid + 256 * it;
          int kl = f4 >> 3, bq = f4 & 7;
          *reinterpret_cast<float4*>(&sh[kl * 36 + bq * 4]) =
              *reinterpret_cast<const float4*>(src + kl * 32 + bq * 4);
        }
      } else {
        float4 z = make_float4(0.f, 0.f, 0.f, 0.f);
#pragma unroll
        for (int it = 0; it < 8; ++it) {
          int f4 = tid + 256 * it;
          *reinterpret_cast<float4*>(&sh[(f4 >> 3) * 36 + (f4 & 7) * 4]) = z;
        }
      }
      __syncthreads();
      // ---- compute: acc[i][j] += sum_k w[r4*4+i][k] * h[k][4*b4+j]
#pragma unroll
      for (int u = 0; u < 4; ++u) {
        int kl = kq * 16 + u * 4;
        float4 h0 = *reinterpret_cast<const float4*>(&sh[(kl + 0) * 36 + b4 * 4]);
        float4 h1 = *reinterpret_cast<const float4*>(&sh[(kl + 1) * 36 + b4 * 4]);
        float4 h2 = *reinterpret_cast<const float4*>(&sh[(kl + 2) * 36 + b4 * 4]);
        float4 h3 = *reinterpret_cast<const float4*>(&sh[(kl + 3) * 36 + b4 * 4]);
#pragma unroll
        for (int i = 0; i < 4; ++i) {
          float4 w = wreg[h][i][u];
          acc4[i].x = fmaf(w.x, h0.x, fmaf(w.y, h1.x, fmaf(w.z, h2.x, fmaf(w.w, h3.x, acc4[i].x))));
          acc4[i].y = fmaf(w.x, h0.y, fmaf(w.y, h1.y, fmaf(w.z, h2.y, fmaf(w.w, h3.y, acc4[i].y))));
          acc4[i].z = fmaf(w.x, h0.z, fmaf(w.y, h1.z, fmaf(w.z, h2.z, fmaf(w.w, h3.z, acc4[i].z))));
          acc4[i].w = fmaf(w.x, h0.w, fmaf(w.y, h1.w, fmaf(w.z, h2.w, fmaf(w.w, h3.w, acc4[i].w))));
        }
      }
      __syncthreads();
    }
    // ---- k-split partials into LDS (alias over hs)
#pragma unroll
    for (int i = 0; i < 4; ++i)
      *reinterpret_cast<float4*>(&sh[kq * 288 + (4 * r4 + i) * 36 + b4 * 4]) = acc4[i];
    __syncthreads();
    // ---- reduce 16 partials + G
    float sum = gpre;
#pragma unroll
    for (int q = 0; q < 16; ++q) sum += sh[q * 288 + rr * 36 + rb];
    sh[4608 + rr * 36 + rb] = sum;
    __syncthreads();
    // ---- LSTM cell (64 threads: 2 cols x 32 batch) — reference op structure, no fma
    if (tid < 64) {
      float gi = sh[4608 + (0 + cd) * 36 + cb];
      float gf = sh[4608 + (2 + cd) * 36 + cb];
      float gg = sh[4608 + (4 + cd) * 36 + cb];
      float go = sh[4608 + (6 + cd) * 36 + cb];
      float a  = __fmul_rn(sig_hi(gf), creg);
      float bb = __fmul_rn(sig_hi(gi), tanh_hi(gg));
      float cn = __fadd_rn(a, bb);
      creg = cn;
      float hn = __fmul_rn(sig_hi(go), tanh_hi(cn));
      Hout[(size_t)t * 16384 + cb * 512 + ccol] = hn;
      hT[pw * 16384 + ccol * 32 + cb] = hn;
      if (ts == len - 1) cst[cb * 512 + ccol] = cn;
    }
    // ---- grid barrier (agent scope; release on arrive, acquire on spin)
    __syncthreads();
    if (tid == 0) {
      unsigned int target = (unsigned int)NBLK * (unsigned int)(ts + 1);
      __hip_atomic_fetch_add(cnt, 1u, __ATOMIC_RELEASE, __HIP_MEMORY_SCOPE_AGENT);
      while (__hip_atomic_load(cnt, __ATOMIC_ACQUIRE, __HIP_MEMORY_SCOPE_AGENT) < target)
        __builtin_amdgcn_s_sleep(4);
    }
    __syncthreads();
  }
}

// ---------------------------------------------------------------- t=0 fix
// Recompute h_0 = cell(src[0] @ wih_l^T + bih_l + bhh_l) with h_-1 = c_-1 = 0.
// Runs LAST: overwrites dst[0..16383] regardless of what happened earlier.
__global__ __launch_bounds__(256) void k_fix3(const float* __restrict__ src,    // [32][512]
                                              const float* __restrict__ wih_l,  // [2048][512]
                                              const float* __restrict__ bih_l,
                                              const float* __restrict__ bhh_l,
                                              float* __restrict__ dst) {        // [32][512]
  int idx = blockIdx.x * 256 + threadIdx.x;   // 0..16383
  int b = idx >> 9, n = idx & 511;
  const float4* x = reinterpret_cast<const float4*>(src + b * 512);
  float d[4];
#pragma unroll
  for (int g = 0; g < 4; ++g) {
    const float4* w = reinterpret_cast<const float4*>(wih_l + (size_t)(g * 512 + n) * 512);
    float s = 0.f;
    for (int k = 0; k < 128; ++k) {
      float4 xv = x[k], wv = w[k];
      s = fmaf(xv.x, wv.x, s); s = fmaf(xv.y, wv.y, s);
      s = fmaf(xv.z, wv.z, s); s = fmaf(xv.w, wv.w, s);
    }
    d[g] = s + bih_l[g * 512 + n] + bhh_l[g * 512 + n];
  }
  // c_-1 = 0: cn = sig(f)*0 + sig(i)*tanh(g)
  float a  = __fmul_rn(sig_hi(d[1]), 0.0f);
  float bb = __fmul_rn(sig_hi(d[0]), tanh_hi(d[2]));
  float cn = __fadd_rn(a, bb);
  float hn = __fmul_rn(sig_hi(d[3]), tanh_hi(cn));
  dst[idx] = hn;
}

// ---------------------------------------------------------------- pack hf/cf
__global__ void k_pack3(const float* __restrict__ H0, const float* __restrict__ outs,
                        const float* __restrict__ cstate, float* __restrict__ hf,
                        float* __restrict__ cf) {
  int i = blockIdx.x * 256 + threadIdx.x;   // 0..16383
  hf[i] = H0[(size_t)1023 * 16384 + i];
  cf[i] = cstate[i];
  hf[16384 + i] = outs[(size_t)1023 * 16384 + i];
  cf[16384 + i] = cstate[16384 + i];
}

// ---------------------------------------------------------------- host
extern "C" void kernel_launch(void* const* d_in, const int* in_sizes, int n_in,
                              void* d_out, int out_size, void* d_ws, size_t ws_size,
                              hipStream_t stream) {
  (void)in_sizes; (void)n_in; (void)out_size;
  const int*   ids = (const int*)d_in[0];
  const float* emb = (const float*)d_in[1];
  const float* wih = (const float*)d_in[2];
  const float* whh = (const float*)d_in[3];
  const float* bih = (const float*)d_in[4];
  const float* bhh = (const float*)d_in[5];

  float* out   = (float*)d_out;
  float* outs  = out;                               // [S][B][H]
  float* hf    = out + (size_t)SS * BB * HH;        // [2][B][H]
  float* cf    = hf + 2 * BB * HH;                  // [2][B][H]
  float* maskf = cf + 2 * BB * HH;                  // [S][B]

  float* ws = (float*)d_ws;
  float* X  = ws;                                   // [S][B][E]
  float* H0 = X + (size_t)SS * BB * EE;             // [S][B][H]
  float* G  = H0 + (size_t)SS * BB * HH;            // [CH*B][2048] ring

  size_t fixedf = (size_t)SS * BB * EE + (size_t)SS * BB * HH + 32768 + 32768 + 512;
  int CH = 256;
  while (CH > 8) {
    size_t need = (fixedf + (size_t)CH * BB * GG) * sizeof(float);
    if (need <= ws_size) break;
    CH >>= 1;
  }
  float* hT = G + (size_t)CH * BB * GG;             // [2][512][32]
  float* cstate = hT + 32768;                       // [2][B][H]
  unsigned int* cnt = (unsigned int*)(cstate + 2 * BB * HH);

  int nch = SS / CH;
  hipMemsetAsync(cnt, 0, sizeof(unsigned int) * (size_t)(2 * nch), stream);
  k_embed3<<<dim3(SS * BB / 4), dim3(256), 0, stream>>>(ids, emb, X, maskf);

  int launchIdx = 0;
  for (int l = 0; l < 2; ++l) {
    const float* Abase = (l == 0) ? X : H0;
    float* HoutL = (l == 0) ? H0 : outs;
    const float* wih_l = wih + (size_t)l * GG * 512;
    const float* whh_l = whh + (size_t)l * GG * 512;
    const float* bih_l = bih + l * GG;
    const float* bhh_l = bhh + l * GG;
    float* cst_l = cstate + (size_t)l * BB * HH;
    for (int c = 0; c < nch; ++c) {
      int s0 = c * CH;
      const float* Achunk = Abase + (size_t)s0 * BB * 512;
      dim3 ggrid(CH * BB / 128, GG / 128);
      k_gemm3<<<ggrid, dim3(256), 0, stream>>>(Achunk, wih_l, bih_l, bhh_l, G);
      unsigned int* cnt_l = cnt + (launchIdx++);
      // plain launch (cooperative API fails in this harness; barrier is custom)
      k_rec3<<<dim3(NBLK), dim3(NTHR), 0, stream>>>(whh_l, G, HoutL, hT, cst_l,
                                                    cnt_l, s0, CH);
    }
  }
  // t=0 rewrite, LAST: layer-0 h_0 from X[0] -> H0[0]; layer-1 h_0 from H0[0] -> outs[0]
  k_fix3<<<dim3(64), dim3(256), 0, stream>>>(X, wih, bih, bhh, H0);
  k_fix3<<<dim3(64), dim3(256), 0, stream>>>(H0, wih + (size_t)GG * 512, bih + GG, bhh + GG, outs);
  k_pack3<<<dim3(64), dim3(256), 0, stream>>>(H0, outs, cstate, hf, cf);
}